// Round 1
// baseline (718.190 us; speedup 1.0000x reference)
//
#include <hip/hip_runtime.h>

#define NPOS 262144  // 512*512

typedef __attribute__((ext_vector_type(8))) short short8;
typedef __attribute__((ext_vector_type(4))) float f32x4;
typedef __attribute__((ext_vector_type(4))) unsigned short us4;
typedef __attribute__((ext_vector_type(4))) unsigned int u32x4;

__device__ __forceinline__ unsigned short f2bf(float f){
  unsigned u = __float_as_uint(f);
  u += 0x7fffu + ((u >> 16) & 1u);
  return (unsigned short)(u >> 16);
}
__device__ __forceinline__ float bf2f(unsigned int h){ return __uint_as_float(h << 16); }
__device__ __forceinline__ float sigm(float x){ return 1.f/(1.f + __expf(-x)); }

#define MFMA16(a,b,c) __builtin_amdgcn_mfma_f32_16x16x32_bf16((a),(b),(c),0,0,0)

// ---------------------------------------------------------------------------
// Prep: fold LN gains into weights. Wc rows: [0,256)=W_lr', [256,512)=W_gate',
// [512,640)=W_og', [640,768)=W_out'.  svec[r]=sum(g*W_row), cvec[r]=sum(b*W_row)+bias.
// One wave per row.
// ---------------------------------------------------------------------------
__global__ __launch_bounds__(256) void k_prep(
    const float* __restrict__ Wlr, const float* __restrict__ b_lr,
    const float* __restrict__ Wg,  const float* __restrict__ b_g,
    const float* __restrict__ Wog, const float* __restrict__ b_og,
    const float* __restrict__ Wout,const float* __restrict__ obias,
    const float* __restrict__ g1, const float* __restrict__ b1,
    const float* __restrict__ g2, const float* __restrict__ b2,
    unsigned short* __restrict__ Wc, float* __restrict__ svec, float* __restrict__ cvec)
{
  int r = blockIdx.x*4 + (threadIdx.x >> 6);
  int l = threadIdx.x & 63;
  const float *W, *gv, *bv; float extra;
  if (r < 256)      { W = Wlr + r*128;         extra = b_lr[r];      gv=g1; bv=b1; }
  else if (r < 512) { W = Wg  + (r-256)*128;   extra = b_g[r-256];   gv=g1; bv=b1; }
  else if (r < 640) { W = Wog + (r-512)*128;   extra = b_og[r-512];  gv=g1; bv=b1; }
  else              { W = Wout+ (r-640)*128;   extra = obias[r-640]; gv=g2; bv=b2; }
  float w0 = W[2*l], w1 = W[2*l+1];
  float p0 = w0 * gv[2*l], p1 = w1 * gv[2*l+1];
  float s  = p0 + p1;
  float cc = w0 * bv[2*l] + w1 * bv[2*l+1];
  Wc[r*128 + 2*l]   = f2bf(p0);
  Wc[r*128 + 2*l+1] = f2bf(p1);
  for (int off=32; off; off>>=1){ s += __shfl_down(s, off); cc += __shfl_down(cc, off); }
  if (l == 0){ svec[r] = s; cvec[r] = cc + extra; }
}

// ---------------------------------------------------------------------------
// Proj: per block = 128 positions. LN1-folded GEMMs Z*Wlr', Z*Wgate' -> combine
// -> left/right bf16 written channel-planar [c][pos] via LDS transpose.
// ---------------------------------------------------------------------------
__global__ __launch_bounds__(256) void k_proj(
    const float* __restrict__ Zraw, const float* __restrict__ Zmask,
    const unsigned short* __restrict__ Wc,
    const float* __restrict__ svec, const float* __restrict__ cvec,
    unsigned short* __restrict__ leftT, unsigned short* __restrict__ rightT)
{
  __shared__ unsigned short zt[128*144];   // raw Z bf16, [pos][d] pad->144
  __shared__ unsigned short tl[128*136];   // transpose buf [chan][pos] pad->136
  __shared__ float mu_s[128], rs_s[128], mask_s[128];
  const int t = threadIdx.x, l = t & 63, w = t >> 6;
  const int wr = w >> 1, wc = w & 1;
  const long pos0 = (long)blockIdx.x * 128;

  { const f32x4* zg = (const f32x4*)(Zraw + pos0*128);
    for (int v=0; v<16; v++){
      int f = v*256 + t, row = f>>5, c4 = f&31;
      f32x4 z = zg[f];
      us4 h; h[0]=f2bf(z[0]); h[1]=f2bf(z[1]); h[2]=f2bf(z[2]); h[3]=f2bf(z[3]);
      *(us4*)&zt[row*144 + c4*4] = h;
    }
  }
  if (t < 128) mask_s[t] = Zmask[pos0 + t];
  __syncthreads();
  if (t < 128){
    float s=0.f, ss=0.f;
    for (int it=0; it<64; it++){
      int c2 = (t + it) & 63;                       // rotated: conflict-free
      unsigned u = *(const unsigned*)&zt[t*144 + c2*2];
      float a = bf2f(u & 0xffffu), b = bf2f(u >> 16);
      s += a + b; ss += a*a + b*b;
    }
    float mu = s * 0.0078125f;
    float var = ss * 0.0078125f - mu*mu;
    mu_s[t] = mu; rs_s[t] = rsqrtf(var + 1e-5f);
  }
  __syncthreads();

  for (int half=0; half<2; half++){
    const unsigned short* Blr = Wc + (half*128)*128;
    const unsigned short* Bgt = Wc + (256 + half*128)*128;
    f32x4 accL[4][4], accG[4][4];
    for (int mt=0; mt<4; mt++) for (int nt=0; nt<4; nt++){
      accL[mt][nt] = (f32x4)(0.f); accG[mt][nt] = (f32x4)(0.f);
    }
    for (int ks=0; ks<4; ks++){
      const int krow = ks*32 + ((l>>4)<<3);
      short8 bl[4], bg[4];
      for (int nt=0; nt<4; nt++){
        int n = wc*64 + nt*16 + (l&15);
        bl[nt] = *(const short8*)(Blr + n*128 + krow);
        bg[nt] = *(const short8*)(Bgt + n*128 + krow);
      }
      for (int mt=0; mt<4; mt++){
        int row = wr*64 + mt*16 + (l&15);
        short8 a = *(const short8*)&zt[row*144 + krow];
        for (int nt=0; nt<4; nt++){
          accL[mt][nt] = MFMA16(a, bl[nt], accL[mt][nt]);
          accG[mt][nt] = MFMA16(a, bg[nt], accG[mt][nt]);
        }
      }
    }
    for (int mt=0; mt<4; mt++){
      int rowb = wr*64 + mt*16 + ((l>>4)<<2);
      for (int nt=0; nt<4; nt++){
        int col = wc*64 + nt*16 + (l&15);
        float sL = svec[half*128 + col],       cL = cvec[half*128 + col];
        float sG = svec[256 + half*128 + col], cG = cvec[256 + half*128 + col];
        us4 h;
        for (int r=0; r<4; r++){
          int row = rowb + r;
          float rs = rs_s[row], rm = rs*mu_s[row];
          float lrv = rs*accL[mt][nt][r] - rm*sL + cL;
          float gv  = sigm(rs*accG[mt][nt][r] - rm*sG + cG);
          h[r] = f2bf(mask_s[row] * lrv * gv);
        }
        *(us4*)&tl[col*136 + rowb] = h;
      }
    }
    __syncthreads();
    unsigned short* dst = half ? rightT : leftT;
    for (int v=0; v<32; v++){
      int f2 = v*256 + t, col = f2>>6, rp = (f2&63)<<1;
      unsigned u = *(const unsigned*)&tl[col*136 + rp];
      *(unsigned*)&dst[(long)col*NPOS + pos0 + rp] = u;
    }
    __syncthreads();
  }
}

// ---------------------------------------------------------------------------
// Triangle: 128 per-channel GEMMs P_c = L_c * R_c^T (512^3 each).
// grid 2048: block = (channel, 128x128 tile). Output planar bf16 [c][i][j].
// ---------------------------------------------------------------------------
__global__ __launch_bounds__(256) void k_tri(
    const unsigned short* __restrict__ leftT, const unsigned short* __restrict__ rightT,
    unsigned short* __restrict__ pP)
{
  __shared__ unsigned short At[128*40];
  __shared__ unsigned short Bt[128*40];
  __shared__ unsigned short pj[128*136];
  const int t = threadIdx.x, l = t & 63, w = t >> 6;
  const int wr = w >> 1, wc = w & 1;
  const int c = blockIdx.x >> 4, tile = blockIdx.x & 15;
  const int ti = (tile >> 2) << 7, tj = (tile & 3) << 7;
  const unsigned short* L = leftT  + (long)c*NPOS + (long)ti*512;
  const unsigned short* R = rightT + (long)c*NPOS + (long)tj*512;
  f32x4 acc[4][4];
  for (int mt=0; mt<4; mt++) for (int nt=0; nt<4; nt++) acc[mt][nt] = (f32x4)(0.f);
  for (int kt=0; kt<16; kt++){
    const int k0 = kt*32;
    __syncthreads();
    for (int v=0; v<2; v++){
      int f = v*256 + t, row = f>>2, kc = f&3;
      *(u32x4*)&At[row*40 + kc*8] = *(const u32x4*)(L + row*512 + k0 + kc*8);
      *(u32x4*)&Bt[row*40 + kc*8] = *(const u32x4*)(R + row*512 + k0 + kc*8);
    }
    __syncthreads();
    const int krow = (l>>4)<<3;
    short8 br[4];
    for (int nt=0; nt<4; nt++)
      br[nt] = *(const short8*)&Bt[(wc*64 + nt*16 + (l&15))*40 + krow];
    for (int mt=0; mt<4; mt++){
      short8 a = *(const short8*)&At[(wr*64 + mt*16 + (l&15))*40 + krow];
      for (int nt=0; nt<4; nt++)
        acc[mt][nt] = MFMA16(a, br[nt], acc[mt][nt]);
    }
  }
  __syncthreads();
  for (int mt=0; mt<4; mt++){
    int rowb = wr*64 + mt*16 + ((l>>4)<<2);
    for (int nt=0; nt<4; nt++){
      int col = wc*64 + nt*16 + (l&15);
      for (int r=0; r<4; r++)
        pj[(rowb+r)*136 + col] = f2bf(acc[mt][nt][r]);
    }
  }
  __syncthreads();
  unsigned short* dst = pP + (long)c*NPOS + (long)ti*512 + tj;
  for (int v=0; v<32; v++){
    int f2 = v*256 + t, row = f2>>6, cp = (f2&63)<<1;
    unsigned u = *(const unsigned*)&pj[row*136 + cp];
    *(unsigned*)&dst[(long)row*512 + cp] = u;
  }
}

// ---------------------------------------------------------------------------
// Out: per block = 128 positions (one i, 128 j). Transpose-stage p planar->[pos][c],
// LN2-folded GEMM p*Wout', LN1-folded GEMM Z*Wog' (gate), residual add.
// ---------------------------------------------------------------------------
__global__ __launch_bounds__(256) void k_out(
    const float* __restrict__ Zraw, const unsigned short* __restrict__ pP,
    const unsigned short* __restrict__ Wc,
    const float* __restrict__ svec, const float* __restrict__ cvec,
    float* __restrict__ out)
{
  __shared__ unsigned short zt[128*144];
  __shared__ unsigned short pt[128*144];
  __shared__ float mu1s[128], rs1s[128], mu2s[128], rs2s[128];
  const int t = threadIdx.x, l = t & 63, w = t >> 6;
  const int wr = w >> 1, wc = w & 1;
  const long pos0 = (long)blockIdx.x * 128;
  const int ib = blockIdx.x >> 2, j0 = (blockIdx.x & 3) << 7;

  { const f32x4* zg = (const f32x4*)(Zraw + pos0*128);
    for (int v=0; v<16; v++){
      int f = v*256 + t, row = f>>5, c4 = f&31;
      f32x4 z = zg[f];
      us4 h; h[0]=f2bf(z[0]); h[1]=f2bf(z[1]); h[2]=f2bf(z[2]); h[3]=f2bf(z[3]);
      *(us4*)&zt[row*144 + c4*4] = h;
    }
  }
  for (int v=0; v<32; v++){
    int f2 = v*256 + t, cch = f2>>6, jp = (f2&63)<<1;
    unsigned u = *(const unsigned*)&pP[(long)cch*NPOS + (long)ib*512 + j0 + jp];
    pt[jp*144 + cch]     = (unsigned short)(u & 0xffffu);
    pt[(jp+1)*144 + cch] = (unsigned short)(u >> 16);
  }
  __syncthreads();
  if (t < 128){
    float s=0.f, ss=0.f;
    for (int it=0; it<64; it++){
      int c2 = (t + it) & 63;
      unsigned u = *(const unsigned*)&zt[t*144 + c2*2];
      float a = bf2f(u & 0xffffu), b = bf2f(u >> 16);
      s += a + b; ss += a*a + b*b;
    }
    float mu = s*0.0078125f, var = ss*0.0078125f - mu*mu;
    mu1s[t] = mu; rs1s[t] = rsqrtf(var + 1e-5f);
  } else {
    int p = t - 128;
    float s=0.f, ss=0.f;
    for (int it=0; it<64; it++){
      int c2 = (p + it) & 63;
      unsigned u = *(const unsigned*)&pt[p*144 + c2*2];
      float a = bf2f(u & 0xffffu), b = bf2f(u >> 16);
      s += a + b; ss += a*a + b*b;
    }
    float mu = s*0.0078125f, var = ss*0.0078125f - mu*mu;
    mu2s[p] = mu; rs2s[p] = rsqrtf(var + 1e-5f);
  }
  __syncthreads();

  const unsigned short* W2  = Wc + 640*128;
  const unsigned short* WgB = Wc + 512*128;
  f32x4 acc1[4][4], acc2[4][4];
  for (int mt=0; mt<4; mt++) for (int nt=0; nt<4; nt++){
    acc1[mt][nt]=(f32x4)(0.f); acc2[mt][nt]=(f32x4)(0.f);
  }
  for (int ks=0; ks<4; ks++){
    const int krow = ks*32 + ((l>>4)<<3);
    short8 bo[4], bg[4];
    for (int nt=0; nt<4; nt++){
      int n = wc*64 + nt*16 + (l&15);
      bo[nt] = *(const short8*)(W2  + n*128 + krow);
      bg[nt] = *(const short8*)(WgB + n*128 + krow);
    }
    for (int mt=0; mt<4; mt++){
      int row = wr*64 + mt*16 + (l&15);
      short8 ap = *(const short8*)&pt[row*144 + krow];
      short8 az = *(const short8*)&zt[row*144 + krow];
      for (int nt=0; nt<4; nt++){
        acc1[mt][nt] = MFMA16(ap, bo[nt], acc1[mt][nt]);
        acc2[mt][nt] = MFMA16(az, bg[nt], acc2[mt][nt]);
      }
    }
  }
  for (int mt=0; mt<4; mt++){
    int rowb = wr*64 + mt*16 + ((l>>4)<<2);
    for (int nt=0; nt<4; nt++){
      int col = wc*64 + nt*16 + (l&15);
      float sO = svec[640 + col], cO = cvec[640 + col];
      float sg = svec[512 + col], cg = cvec[512 + col];
      for (int r=0; r<4; r++){
        int row = rowb + r;
        float ab = rs2s[row]*acc1[mt][nt][r] - rs2s[row]*mu2s[row]*sO + cO;
        float gv = sigm(rs1s[row]*acc2[mt][nt][r] - rs1s[row]*mu1s[row]*sg + cg);
        long gidx = (pos0 + row)*128 + col;
        out[gidx] = Zraw[gidx] + gv*ab;
      }
    }
  }
}

// ---------------------------------------------------------------------------
extern "C" void kernel_launch(void* const* d_in, const int* in_sizes, int n_in,
                              void* d_out, int out_size, void* d_ws, size_t ws_size,
                              hipStream_t stream)
{
  (void)in_sizes; (void)n_in; (void)out_size; (void)ws_size;
  const float* Zraw  = (const float*)d_in[0];
  const float* Zmask = (const float*)d_in[1];
  const float* g1    = (const float*)d_in[2];
  const float* b1    = (const float*)d_in[3];
  const float* Wlr   = (const float*)d_in[4];
  const float* blr   = (const float*)d_in[5];
  const float* Wg    = (const float*)d_in[6];
  const float* bg    = (const float*)d_in[7];
  const float* Wog   = (const float*)d_in[8];
  const float* bog   = (const float*)d_in[9];
  const float* g2    = (const float*)d_in[10];
  const float* b2    = (const float*)d_in[11];
  const float* Wout  = (const float*)d_in[12];
  const float* obias = (const float*)d_in[13];

  char* ws = (char*)d_ws;
  unsigned short* leftT  = (unsigned short*)(ws);
  unsigned short* rightT = (unsigned short*)(ws + 67108864L);
  unsigned short* pP     = (unsigned short*)(ws + 134217728L);
  unsigned short* Wc     = (unsigned short*)(ws + 201326592L);
  float* svec            = (float*)(ws + 201326592L + 196608L);
  float* cvec            = (float*)(ws + 201326592L + 196608L + 4096L);
  float* out = (float*)d_out;

  k_prep<<<192, 256, 0, stream>>>(Wlr, blr, Wg, bg, Wog, bog, Wout, obias,
                                  g1, b1, g2, b2, Wc, svec, cvec);
  k_proj<<<2048, 256, 0, stream>>>(Zraw, Zmask, Wc, svec, cvec, leftT, rightT);
  k_tri<<<2048, 256, 0, stream>>>(leftT, rightT, pP);
  k_out<<<2048, 256, 0, stream>>>(Zraw, pP, Wc, svec, cvec, out);
}

// Round 2
// 605.953 us; speedup vs baseline: 1.1852x; 1.1852x over previous
//
#include <hip/hip_runtime.h>

#define NPOS 262144  // 512*512

typedef __attribute__((ext_vector_type(8))) short short8;
typedef __attribute__((ext_vector_type(4))) float f32x4;
typedef __attribute__((ext_vector_type(4))) unsigned short us4;
typedef __attribute__((ext_vector_type(4))) unsigned int u32x4;

__device__ __forceinline__ unsigned short f2bf(float f){
  unsigned u = __float_as_uint(f);
  u += 0x7fffu + ((u >> 16) & 1u);
  return (unsigned short)(u >> 16);
}
__device__ __forceinline__ float bf2f(unsigned int h){ return __uint_as_float(h << 16); }
__device__ __forceinline__ float sigm(float x){ return 1.f/(1.f + __expf(-x)); }

#define MFMA16(a,b,c) __builtin_amdgcn_mfma_f32_16x16x32_bf16((a),(b),(c),0,0,0)

// ---------------------------------------------------------------------------
// Prep: fold LN gains into weights. Wc rows: [0,256)=W_lr', [256,512)=W_gate',
// [512,640)=W_og', [640,768)=W_out'.  svec[r]=sum(g*W_row), cvec[r]=sum(b*W_row)+bias.
// ---------------------------------------------------------------------------
__global__ __launch_bounds__(256) void k_prep(
    const float* __restrict__ Wlr, const float* __restrict__ b_lr,
    const float* __restrict__ Wg,  const float* __restrict__ b_g,
    const float* __restrict__ Wog, const float* __restrict__ b_og,
    const float* __restrict__ Wout,const float* __restrict__ obias,
    const float* __restrict__ g1, const float* __restrict__ b1,
    const float* __restrict__ g2, const float* __restrict__ b2,
    unsigned short* __restrict__ Wc, float* __restrict__ svec, float* __restrict__ cvec)
{
  int r = blockIdx.x*4 + (threadIdx.x >> 6);
  int l = threadIdx.x & 63;
  const float *W, *gv, *bv; float extra;
  if (r < 256)      { W = Wlr + r*128;         extra = b_lr[r];      gv=g1; bv=b1; }
  else if (r < 512) { W = Wg  + (r-256)*128;   extra = b_g[r-256];   gv=g1; bv=b1; }
  else if (r < 640) { W = Wog + (r-512)*128;   extra = b_og[r-512];  gv=g1; bv=b1; }
  else              { W = Wout+ (r-640)*128;   extra = obias[r-640]; gv=g2; bv=b2; }
  float w0 = W[2*l], w1 = W[2*l+1];
  float p0 = w0 * gv[2*l], p1 = w1 * gv[2*l+1];
  float s  = p0 + p1;
  float cc = w0 * bv[2*l] + w1 * bv[2*l+1];
  Wc[r*128 + 2*l]   = f2bf(p0);
  Wc[r*128 + 2*l+1] = f2bf(p1);
  for (int off=32; off; off>>=1){ s += __shfl_down(s, off); cc += __shfl_down(cc, off); }
  if (l == 0){ svec[r] = s; cvec[r] = cc + extra; }
}

// ---------------------------------------------------------------------------
// Proj: per block = 128 positions. LN1-folded GEMMs Z*Wlr', Z*Wgate' -> combine
// -> left/right bf16 written channel-planar [c][pos] via LDS transpose.
// ---------------------------------------------------------------------------
__global__ __launch_bounds__(256) void k_proj(
    const float* __restrict__ Zraw, const float* __restrict__ Zmask,
    const unsigned short* __restrict__ Wc,
    const float* __restrict__ svec, const float* __restrict__ cvec,
    unsigned short* __restrict__ leftT, unsigned short* __restrict__ rightT)
{
  __shared__ unsigned short zt[128*144];   // raw Z bf16, [pos][d] pad->144
  __shared__ unsigned short tl[128*132];   // transpose buf [chan][pos] pitch 132 (66 dw)
  __shared__ float mu_s[128], rs_s[128], mask_s[128];
  __shared__ float ps[256], pss[256];
  const int t = threadIdx.x, l = t & 63, w = t >> 6;
  const int wr = w >> 1, wc = w & 1;
  const long pos0 = (long)blockIdx.x * 128;

  { const f32x4* zg = (const f32x4*)(Zraw + pos0*128);
    for (int v=0; v<16; v++){
      int f = v*256 + t, row = f>>5, c4 = f&31;
      f32x4 z = zg[f];
      us4 h; h[0]=f2bf(z[0]); h[1]=f2bf(z[1]); h[2]=f2bf(z[2]); h[3]=f2bf(z[3]);
      *(us4*)&zt[row*144 + c4*4] = h;
    }
  }
  if (t < 128) mask_s[t] = Zmask[pos0 + t];
  __syncthreads();
  { // LN1 stats: 2 threads per row, rotated conflict-free access
    int sr = t & 127, hi = t >> 7;
    float s=0.f, ss=0.f;
    for (int it=hi*32; it<hi*32+32; it++){
      int c2 = (sr + it) & 63;
      unsigned u = *(const unsigned*)&zt[sr*144 + c2*2];
      float a = bf2f(u & 0xffffu), b = bf2f(u >> 16);
      s += a + b; ss += a*a + b*b;
    }
    ps[t] = s; pss[t] = ss;
  }
  __syncthreads();
  if (t < 128){
    float s = ps[t] + ps[t+128], ss = pss[t] + pss[t+128];
    float mu = s * 0.0078125f;
    float var = ss * 0.0078125f - mu*mu;
    mu_s[t] = mu; rs_s[t] = rsqrtf(var + 1e-5f);
  }
  __syncthreads();

  for (int half=0; half<2; half++){
    const unsigned short* Blr = Wc + (half*128)*128;
    const unsigned short* Bgt = Wc + (256 + half*128)*128;
    f32x4 accL[4][4], accG[4][4];
    for (int mt=0; mt<4; mt++) for (int nt=0; nt<4; nt++){
      accL[mt][nt] = (f32x4)(0.f); accG[mt][nt] = (f32x4)(0.f);
    }
    for (int ks=0; ks<4; ks++){
      const int krow = ks*32 + ((l>>4)<<3);
      short8 bl[4], bg[4];
      for (int nt=0; nt<4; nt++){
        int n = wc*64 + nt*16 + (l&15);
        bl[nt] = *(const short8*)(Blr + n*128 + krow);
        bg[nt] = *(const short8*)(Bgt + n*128 + krow);
      }
      for (int mt=0; mt<4; mt++){
        int row = wr*64 + mt*16 + (l&15);
        short8 a = *(const short8*)&zt[row*144 + krow];
        for (int nt=0; nt<4; nt++){
          accL[mt][nt] = MFMA16(a, bl[nt], accL[mt][nt]);
          accG[mt][nt] = MFMA16(a, bg[nt], accG[mt][nt]);
        }
      }
    }
    for (int mt=0; mt<4; mt++){
      int rowb = wr*64 + mt*16 + ((l>>4)<<2);
      for (int nt=0; nt<4; nt++){
        int col = wc*64 + nt*16 + (l&15);
        float sL = svec[half*128 + col],       cL = cvec[half*128 + col];
        float sG = svec[256 + half*128 + col], cG = cvec[256 + half*128 + col];
        us4 h;
        for (int r=0; r<4; r++){
          int row = rowb + r;
          float rs = rs_s[row], rm = rs*mu_s[row];
          float lrv = rs*accL[mt][nt][r] - rm*sL + cL;
          float gv  = sigm(rs*accG[mt][nt][r] - rm*sG + cG);
          h[r] = f2bf(mask_s[row] * lrv * gv);
        }
        *(us4*)&tl[col*132 + rowb] = h;
      }
    }
    __syncthreads();
    unsigned short* dst = half ? rightT : leftT;
    for (int v=0; v<32; v++){
      int f2 = v*256 + t, col = f2>>6, rp = (f2&63)<<1;
      unsigned u = *(const unsigned*)&tl[col*132 + rp];
      *(unsigned*)&dst[(long)col*NPOS + pos0 + rp] = u;
    }
    __syncthreads();
  }
}

// ---------------------------------------------------------------------------
// Triangle: 128 per-channel GEMMs P_c = L_c * R_c^T (512^3 each).
// grid 2048: block = (channel, 128x128 tile). Output planar bf16 [c][i][j].
// K-chunk = 64 (halves barrier count vs K=32).
// ---------------------------------------------------------------------------
__global__ __launch_bounds__(256) void k_tri(
    const unsigned short* __restrict__ leftT, const unsigned short* __restrict__ rightT,
    unsigned short* __restrict__ pP)
{
  __shared__ unsigned short At[128*72];
  __shared__ unsigned short Bt[128*72];
  __shared__ unsigned short pj[128*132];
  const int t = threadIdx.x, l = t & 63, w = t >> 6;
  const int wr = w >> 1, wc = w & 1;
  const int c = blockIdx.x >> 4, tile = blockIdx.x & 15;
  const int ti = (tile >> 2) << 7, tj = (tile & 3) << 7;
  const unsigned short* L = leftT  + (long)c*NPOS + (long)ti*512;
  const unsigned short* R = rightT + (long)c*NPOS + (long)tj*512;
  f32x4 acc[4][4];
  for (int mt=0; mt<4; mt++) for (int nt=0; nt<4; nt++) acc[mt][nt] = (f32x4)(0.f);
  for (int kt=0; kt<8; kt++){
    const int k0 = kt*64;
    __syncthreads();
    for (int v=0; v<4; v++){
      int f = v*256 + t, row = f>>3, kc = f&7;
      *(u32x4*)&At[row*72 + kc*8] = *(const u32x4*)(L + row*512 + k0 + kc*8);
      *(u32x4*)&Bt[row*72 + kc*8] = *(const u32x4*)(R + row*512 + k0 + kc*8);
    }
    __syncthreads();
    for (int ks2=0; ks2<2; ks2++){
      const int krow = ks2*32 + ((l>>4)<<3);
      short8 br[4];
      for (int nt=0; nt<4; nt++)
        br[nt] = *(const short8*)&Bt[(wc*64 + nt*16 + (l&15))*72 + krow];
      for (int mt=0; mt<4; mt++){
        short8 a = *(const short8*)&At[(wr*64 + mt*16 + (l&15))*72 + krow];
        for (int nt=0; nt<4; nt++)
          acc[mt][nt] = MFMA16(a, br[nt], acc[mt][nt]);
      }
    }
  }
  __syncthreads();
  for (int mt=0; mt<4; mt++){
    int rowb = wr*64 + mt*16 + ((l>>4)<<2);
    for (int nt=0; nt<4; nt++){
      int col = wc*64 + nt*16 + (l&15);
      for (int r=0; r<4; r++)
        pj[(rowb+r)*132 + col] = f2bf(acc[mt][nt][r]);
    }
  }
  __syncthreads();
  unsigned short* dst = pP + (long)c*NPOS + (long)ti*512 + tj;
  for (int v=0; v<32; v++){
    int f2 = v*256 + t, row = f2>>6, cp = (f2&63)<<1;
    unsigned u = *(const unsigned*)&pj[row*132 + cp];
    *(unsigned*)&dst[(long)row*512 + cp] = u;
  }
}

// ---------------------------------------------------------------------------
// Out: per block = 128 positions (one i, 128 j). p staged [c][j] in LDS with
// odd dword pitch (65 dw) -> conflict-free u32 staging writes, conflict-free
// column stats, conflict-free scalar-u16 A-fragment gathers. Then LN2-folded
// GEMM p*Wout', LN1-folded GEMM Z*Wog' (gate), residual add.
// ---------------------------------------------------------------------------
__global__ __launch_bounds__(256) void k_out(
    const float* __restrict__ Zraw, const unsigned short* __restrict__ pP,
    const unsigned short* __restrict__ Wc,
    const float* __restrict__ svec, const float* __restrict__ cvec,
    float* __restrict__ out)
{
  __shared__ unsigned short zt[128*144];   // Z bf16 [pos][c]
  __shared__ unsigned pt[128*65];          // p bf16 [c][j], row = 65 dwords (64 data + 1 pad)
  __shared__ float sb[256*4];
  __shared__ float mu1s[128], rs1s[128], mu2s[128], rs2s[128];
  const int t = threadIdx.x, l = t & 63, w = t >> 6;
  const int wr = w >> 1, wc = w & 1;
  const long pos0 = (long)blockIdx.x * 128;
  const int ib = blockIdx.x >> 2, j0 = (blockIdx.x & 3) << 7;

  { const f32x4* zg = (const f32x4*)(Zraw + pos0*128);
    for (int v=0; v<16; v++){
      int f = v*256 + t, row = f>>5, c4 = f&31;
      f32x4 z = zg[f];
      us4 h; h[0]=f2bf(z[0]); h[1]=f2bf(z[1]); h[2]=f2bf(z[2]); h[3]=f2bf(z[3]);
      *(us4*)&zt[row*144 + c4*4] = h;
    }
  }
  // stage p tile: per wave one channel row at a time, consecutive dwords -> conflict-free
  for (int v=0; v<32; v++){
    int f = v*256 + t, cch = f>>6, j2 = f&63;
    pt[cch*65 + j2] = *(const unsigned*)&pP[(long)cch*NPOS + (long)ib*512 + j0 + 2*j2];
  }
  __syncthreads();

  { // LN1 stats on zt rows (2 threads/row, rotated)
    int sr = t & 127, hi = t >> 7;
    float s=0.f, ss=0.f;
    for (int it=hi*32; it<hi*32+32; it++){
      int c2 = (sr + it) & 63;
      unsigned u = *(const unsigned*)&zt[sr*144 + c2*2];
      float a = bf2f(u & 0xffffu), b = bf2f(u >> 16);
      s += a + b; ss += a*a + b*b;
    }
    ps_store: ;
    sb[t*4+0] = s; sb[t*4+1] = ss;
    // LN2 partials on pt columns (4 threads/column-pair, conflict-free)
    int jp = t & 63, ch = t >> 6;
    float s0=0.f, ss0=0.f, s1=0.f, ss1=0.f;
    for (int cc=ch*32; cc<ch*32+32; cc++){
      unsigned u = pt[cc*65 + jp];
      float a = bf2f(u & 0xffffu), b = bf2f(u >> 16);
      s0 += a; ss0 += a*a; s1 += b; ss1 += b*b;
    }
    sb[t*4+2] = s0 + s1*0.f; // keep layout: store below after sync? no — need 6 slots; pack:
    // We need both LN1 (2 floats) and LN2 (4 floats) partials; reuse sb with two syncs.
    __syncthreads();
    if (t < 128){
      float S = sb[t*4+0] + sb[(t+128)*4+0];
      float SS = sb[t*4+1] + sb[(t+128)*4+1];
      float mu = S*0.0078125f, var = SS*0.0078125f - mu*mu;
      mu1s[t] = mu; rs1s[t] = rsqrtf(var + 1e-5f);
    }
    __syncthreads();
    sb[t*4+0] = s0; sb[t*4+1] = ss0; sb[t*4+2] = s1; sb[t*4+3] = ss1;
    __syncthreads();
    if (t >= 128){
      int j = t - 128, jpp = j >> 1, o = j & 1;
      float S=0.f, SS=0.f;
      for (int ww=0; ww<4; ww++){
        S  += sb[(ww*64 + jpp)*4 + 2*o];
        SS += sb[(ww*64 + jpp)*4 + 2*o + 1];
      }
      float mu = S*0.0078125f, var = SS*0.0078125f - mu*mu;
      mu2s[j] = mu; rs2s[j] = rsqrtf(var + 1e-5f);
    }
  }
  __syncthreads();

  const unsigned short* W2  = Wc + 640*128;
  const unsigned short* WgB = Wc + 512*128;
  const unsigned short* pt16 = (const unsigned short*)pt;
  f32x4 acc1[4][4], acc2[4][4];
  for (int mt=0; mt<4; mt++) for (int nt=0; nt<4; nt++){
    acc1[mt][nt]=(f32x4)(0.f); acc2[mt][nt]=(f32x4)(0.f);
  }
  for (int ks=0; ks<4; ks++){
    const int krow = ks*32 + ((l>>4)<<3);
    short8 bo[4], bg[4];
    for (int nt=0; nt<4; nt++){
      int n = wc*64 + nt*16 + (l&15);
      bo[nt] = *(const short8*)(W2  + n*128 + krow);
      bg[nt] = *(const short8*)(WgB + n*128 + krow);
    }
    for (int mt=0; mt<4; mt++){
      int row = wr*64 + mt*16 + (l&15);
      // A-frag for out GEMM: gather 8 channels (krow..krow+7) of column j=row
      short8 ap;
      #pragma unroll
      for (int m=0; m<8; m++)
        ap[m] = (short)pt16[(krow+m)*130 + row];
      short8 az = *(const short8*)&zt[row*144 + krow];
      for (int nt=0; nt<4; nt++){
        acc1[mt][nt] = MFMA16(ap, bo[nt], acc1[mt][nt]);
        acc2[mt][nt] = MFMA16(az, bg[nt], acc2[mt][nt]);
      }
    }
  }
  for (int mt=0; mt<4; mt++){
    int rowb = wr*64 + mt*16 + ((l>>4)<<2);
    for (int nt=0; nt<4; nt++){
      int col = wc*64 + nt*16 + (l&15);
      float sO = svec[640 + col], cO = cvec[640 + col];
      float sg = svec[512 + col], cg = cvec[512 + col];
      for (int r=0; r<4; r++){
        int row = rowb + r;
        float ab = rs2s[row]*acc1[mt][nt][r] - rs2s[row]*mu2s[row]*sO + cO;
        float gv = sigm(rs1s[row]*acc2[mt][nt][r] - rs1s[row]*mu1s[row]*sg + cg);
        long gidx = (pos0 + row)*128 + col;
        out[gidx] = Zraw[gidx] + gv*ab;
      }
    }
  }
}

// ---------------------------------------------------------------------------
extern "C" void kernel_launch(void* const* d_in, const int* in_sizes, int n_in,
                              void* d_out, int out_size, void* d_ws, size_t ws_size,
                              hipStream_t stream)
{
  (void)in_sizes; (void)n_in; (void)out_size; (void)ws_size;
  const float* Zraw  = (const float*)d_in[0];
  const float* Zmask = (const float*)d_in[1];
  const float* g1    = (const float*)d_in[2];
  const float* b1    = (const float*)d_in[3];
  const float* Wlr   = (const float*)d_in[4];
  const float* blr   = (const float*)d_in[5];
  const float* Wg    = (const float*)d_in[6];
  const float* bg    = (const float*)d_in[7];
  const float* Wog   = (const float*)d_in[8];
  const float* bog   = (const float*)d_in[9];
  const float* g2    = (const float*)d_in[10];
  const float* b2    = (const float*)d_in[11];
  const float* Wout  = (const float*)d_in[12];
  const float* obias = (const float*)d_in[13];

  char* ws = (char*)d_ws;
  unsigned short* leftT  = (unsigned short*)(ws);
  unsigned short* rightT = (unsigned short*)(ws + 67108864L);
  unsigned short* pP     = (unsigned short*)(ws + 134217728L);
  unsigned short* Wc     = (unsigned short*)(ws + 201326592L);
  float* svec            = (float*)(ws + 201326592L + 196608L);
  float* cvec            = (float*)(ws + 201326592L + 196608L + 4096L);
  float* out = (float*)d_out;

  k_prep<<<192, 256, 0, stream>>>(Wlr, blr, Wg, bg, Wog, bog, Wout, obias,
                                  g1, b1, g2, b2, Wc, svec, cvec);
  k_proj<<<2048, 256, 0, stream>>>(Zraw, Zmask, Wc, svec, cvec, leftT, rightT);
  k_tri<<<2048, 256, 0, stream>>>(leftT, rightT, pP);
  k_out<<<2048, 256, 0, stream>>>(Zraw, pP, Wc, svec, cvec, out);
}